// Round 3
// baseline (2092.482 us; speedup 1.0000x reference)
//
#include <hip/hip_runtime.h>
#include <hip/hip_bf16.h>

#define DIM 256
#define HEADS 8
#define DHEAD 32
#define SEQ 2048
#define BATCH 2
#define NROWS (BATCH*SEQ)    // 4096 total rows
#define EPS 1e-5f

// ---------------------------------------------------------------------------
// Kernel 1: q/k/v = x @ {Wq,Wk,Wv}.  16 rows per WG, blockIdx.y picks matrix.
// Inputs fp32, outputs fp32 (reference dtypes are float32 throughout).
// ---------------------------------------------------------------------------
__global__ void qkv_proj(const float* __restrict__ x,
                         const float* __restrict__ Wq,
                         const float* __restrict__ Wk,
                         const float* __restrict__ Wv,
                         float* __restrict__ qo,
                         float* __restrict__ ko,
                         float* __restrict__ vo) {
    __shared__ float xs[16][DIM];
    const int t  = threadIdx.x;
    const int r0 = blockIdx.x * 16;
    const float* W = (blockIdx.y == 0) ? Wq : (blockIdx.y == 1) ? Wk : Wv;
    float* out     = (blockIdx.y == 0) ? qo : (blockIdx.y == 1) ? ko : vo;

    for (int idx = t; idx < 16 * DIM; idx += 256) {
        xs[idx >> 8][idx & 255] = x[(size_t)(r0 + (idx >> 8)) * DIM + (idx & 255)];
    }
    __syncthreads();

    float acc[16];
#pragma unroll
    for (int r = 0; r < 16; r++) acc[r] = 0.f;

    for (int kk = 0; kk < DIM; kk++) {
        float w = W[(size_t)kk * DIM + t];
#pragma unroll
        for (int r = 0; r < 16; r++) acc[r] += xs[r][kk] * w;  // xs broadcast
    }
#pragma unroll
    for (int r = 0; r < 16; r++) out[(size_t)(r0 + r) * DIM + t] = acc[r];
}

// ---------------------------------------------------------------------------
// Kernel 2: flash-style attention.  One WG = 16 q-rows of one (b,h).
// attout[b, i, h*256 + d] = sum_j softmax_j(q_i . k_j * scale) * v[b, j, d]
// ---------------------------------------------------------------------------
__global__ void attn_kernel(const float* __restrict__ q,
                            const float* __restrict__ k,
                            const float* __restrict__ v,
                            float* __restrict__ attout) {
    __shared__ float qs[16][33];    // padded: conflict-free [r][d] scans
    __shared__ float ks[32][33];
    __shared__ float vs[32][256];   // column read vs[j][t]: lane t -> distinct banks
    __shared__ float sbuf[16][36];  // stride 36: rows 16B-aligned for float4 reads
    __shared__ float mrow[16], lrow[16], arow[16];

    const int t  = threadIdx.x;
    const int i0 = blockIdx.x * 16;
    const int h  = blockIdx.y;
    const int b  = blockIdx.z;
    const size_t base = (size_t)b * SEQ;
    const float scale = 0.17677669529663687f;  // 1/sqrt(32)

    for (int idx = t; idx < 16 * 32; idx += 256) {
        int r = idx >> 5, d = idx & 31;
        qs[r][d] = q[(base + i0 + r) * DIM + h * DHEAD + d] * scale;  // fold scale
    }
    if (t < 16) { mrow[t] = -1e30f; lrow[t] = 0.f; }

    float acc[16];
#pragma unroll
    for (int r = 0; r < 16; r++) acc[r] = 0.f;

    for (int jt = 0; jt < SEQ / 32; jt++) {
        const int j0 = jt * 32;
        __syncthreads();  // protects prev iteration's reads + first-iter init
        for (int idx = t; idx < 32 * 32; idx += 256) {
            int j = idx >> 5, d = idx & 31;
            ks[j][d] = k[(base + j0 + j) * DIM + h * DHEAD + d];
        }
        for (int idx = t; idx < 32 * 256; idx += 256) {
            int j = idx >> 8, c = idx & 255;
            vs[j][c] = v[(base + j0 + j) * DIM + c];
        }
        __syncthreads();

        // scores: 16x32 values, 2 per thread
#pragma unroll
        for (int p = 0; p < 2; p++) {
            int idx = t + p * 256;
            int r = idx >> 5, j = idx & 31;
            float s = 0.f;
#pragma unroll
            for (int d = 0; d < 32; d++) s += qs[r][d] * ks[j][d];
            sbuf[r][j] = s;
        }
        __syncthreads();

        // online softmax update, one thread per row
        if (t < 16) {
            const int r = t;
            float mt = mrow[r];
            for (int j = 0; j < 32; j++) mt = fmaxf(mt, sbuf[r][j]);
            float a  = __expf(mrow[r] - mt);
            float ls = 0.f;
            for (int j = 0; j < 32; j++) {
                float p2 = __expf(sbuf[r][j] - mt);
                sbuf[r][j] = p2;
                ls += p2;
            }
            lrow[r] = lrow[r] * a + ls;
            mrow[r] = mt;
            arow[r] = a;
        }
        __syncthreads();

        // O accumulate: thread t owns column t of all 16 rows.
        // j-outer with register-cached vs + float4 broadcast sbuf reads.
#pragma unroll
        for (int r = 0; r < 16; r++) acc[r] *= arow[r];
#pragma unroll
        for (int j4 = 0; j4 < 8; j4++) {
            float vv0 = vs[j4 * 4 + 0][t];
            float vv1 = vs[j4 * 4 + 1][t];
            float vv2 = vs[j4 * 4 + 2][t];
            float vv3 = vs[j4 * 4 + 3][t];
#pragma unroll
            for (int r = 0; r < 16; r++) {
                float4 s4 = *(const float4*)&sbuf[r][j4 * 4];
                acc[r] += s4.x * vv0 + s4.y * vv1 + s4.z * vv2 + s4.w * vv3;
            }
        }
    }

#pragma unroll
    for (int r = 0; r < 16; r++) {
        attout[(base + i0 + r) * (size_t)(HEADS * DIM) + h * DIM + t] = acc[r] / lrow[r];
    }
}

// ---------------------------------------------------------------------------
// Kernel 3: out2 = attout @ Wo + x ; ln1 = LayerNorm(out2) * gamma1
// ---------------------------------------------------------------------------
__global__ void wo_ln(const float* __restrict__ attout,
                      const float* __restrict__ Wo,
                      const float* __restrict__ x,
                      const float* __restrict__ gamma1,
                      float* __restrict__ ln1) {
    __shared__ float as_[16][128];
    __shared__ float ob[16][257];   // 257 stride: conflict-free row scans
    __shared__ float mu[16], rs[16];
    const int t  = threadIdx.x;
    const int r0 = blockIdx.x * 16;

    float acc[16];
#pragma unroll
    for (int r = 0; r < 16; r++) acc[r] = 0.f;

    for (int kt = 0; kt < HEADS * DIM; kt += 128) {
        __syncthreads();
        for (int idx = t; idx < 16 * 128; idx += 256) {
            int r = idx >> 7, c = idx & 127;
            as_[r][c] = attout[(size_t)(r0 + r) * (HEADS * DIM) + kt + c];
        }
        __syncthreads();
        for (int kk = 0; kk < 128; kk++) {
            float w = Wo[(size_t)(kt + kk) * DIM + t];
#pragma unroll
            for (int r = 0; r < 16; r++) acc[r] += as_[r][kk] * w;
        }
    }
#pragma unroll
    for (int r = 0; r < 16; r++) {
        acc[r] += x[(size_t)(r0 + r) * DIM + t];
        ob[r][t] = acc[r];
    }
    __syncthreads();
    if (t < 16) {
        float s = 0.f, s2 = 0.f;
        for (int c = 0; c < DIM; c++) { float vv = ob[t][c]; s += vv; s2 += vv * vv; }
        float m = s * (1.0f / DIM);
        float var = s2 * (1.0f / DIM) - m * m;
        mu[t] = m;
        rs[t] = rsqrtf(var + EPS);
    }
    __syncthreads();
    const float g = gamma1[t];
#pragma unroll
    for (int r = 0; r < 16; r++) {
        ln1[(size_t)(r0 + r) * DIM + t] = (ob[r][t] - mu[r]) * rs[r] * g;
    }
}

// ---------------------------------------------------------------------------
// Kernel 4: y = relu(ln1 @ Wf1) @ Wf2 ; out = LayerNorm(y) * gamma2  (fp32 out)
// ---------------------------------------------------------------------------
__global__ void ffn_ln(const float* __restrict__ ln1,
                       const float* __restrict__ Wf1,
                       const float* __restrict__ Wf2,
                       const float* __restrict__ gamma2,
                       float* __restrict__ out) {
    __shared__ float xs[16][257];
    __shared__ float hs[16][512];
    __shared__ float mu[16], rs[16];
    const int t  = threadIdx.x;
    const int r0 = blockIdx.x * 16;

    for (int idx = t; idx < 16 * DIM; idx += 256) {
        int r = idx >> 8, c = idx & 255;
        xs[r][c] = ln1[(size_t)(r0 + r) * DIM + c];
    }
    __syncthreads();

    float h0[16], h1[16];
#pragma unroll
    for (int r = 0; r < 16; r++) { h0[r] = 0.f; h1[r] = 0.f; }
    for (int kk = 0; kk < DIM; kk++) {
        float w0 = Wf1[(size_t)kk * 512 + t];
        float w1 = Wf1[(size_t)kk * 512 + t + 256];
#pragma unroll
        for (int r = 0; r < 16; r++) {
            float xv = xs[r][kk];
            h0[r] += xv * w0;
            h1[r] += xv * w1;
        }
    }
#pragma unroll
    for (int r = 0; r < 16; r++) {
        hs[r][t]       = fmaxf(h0[r], 0.f);
        hs[r][t + 256] = fmaxf(h1[r], 0.f);
    }
    __syncthreads();

    float acc[16];
#pragma unroll
    for (int r = 0; r < 16; r++) acc[r] = 0.f;
    for (int kk = 0; kk < 512; kk++) {
        float w = Wf2[(size_t)kk * DIM + t];
#pragma unroll
        for (int r = 0; r < 16; r++) acc[r] += hs[r][kk] * w;  // hs broadcast
    }

    // LayerNorm 2 (reuse xs as the row buffer)
#pragma unroll
    for (int r = 0; r < 16; r++) xs[r][t] = acc[r];
    __syncthreads();
    if (t < 16) {
        float s = 0.f, s2 = 0.f;
        for (int c = 0; c < DIM; c++) { float vv = xs[t][c]; s += vv; s2 += vv * vv; }
        float m = s * (1.0f / DIM);
        float var = s2 * (1.0f / DIM) - m * m;
        mu[t] = m;
        rs[t] = rsqrtf(var + EPS);
    }
    __syncthreads();
    const float g = gamma2[t];
#pragma unroll
    for (int r = 0; r < 16; r++) {
        out[(size_t)(r0 + r) * DIM + t] = (xs[r][t] - mu[r]) * rs[r] * g;
    }
}

// ---------------------------------------------------------------------------
extern "C" void kernel_launch(void* const* d_in, const int* in_sizes, int n_in,
                              void* d_out, int out_size, void* d_ws, size_t ws_size,
                              hipStream_t stream) {
    const float* x      = (const float*)d_in[0];
    const float* Wq     = (const float*)d_in[1];
    const float* Wk     = (const float*)d_in[2];
    const float* Wv     = (const float*)d_in[3];
    const float* Wo     = (const float*)d_in[4];
    const float* Wf1    = (const float*)d_in[5];
    const float* Wf2    = (const float*)d_in[6];
    const float* gamma1 = (const float*)d_in[7];
    const float* gamma2 = (const float*)d_in[8];
    float* out = (float*)d_out;

    // fp32 workspace layout (floats):
    float* wsf    = (float*)d_ws;
    float* qb     = wsf;                       // 4096*256
    float* kb     = wsf + 1048576;             // 4096*256
    float* vb     = wsf + 2097152;             // 4096*256
    float* attout = wsf + 3145728;             // 4096*2048
    float* ln1    = wsf + 11534336;            // 4096*256
    // total: 12,582,912 floats = 48 MiB

    qkv_proj<<<dim3(NROWS / 16, 3), 256, 0, stream>>>(x, Wq, Wk, Wv, qb, kb, vb);
    attn_kernel<<<dim3(SEQ / 16, HEADS, BATCH), 256, 0, stream>>>(qb, kb, vb, attout);
    wo_ln<<<NROWS / 16, 256, 0, stream>>>(attout, Wo, x, gamma1, ln1);
    ffn_ln<<<NROWS / 16, 256, 0, stream>>>(ln1, Wf1, Wf2, gamma2, out);
}

// Round 4
// 505.151 us; speedup vs baseline: 4.1423x; 4.1423x over previous
//
#include <hip/hip_runtime.h>
#include <hip/hip_bf16.h>

#define DIM 256
#define HEADS 8
#define DHEAD 32
#define SEQ 2048
#define BATCH 2
#define NROWS (BATCH*SEQ)    // 4096 total rows
#define EPS 1e-5f

typedef __attribute__((ext_vector_type(8))) short bf16x8;   // MFMA A/B frag (4 VGPRs)
typedef __attribute__((ext_vector_type(4))) float f32x4;    // MFMA C/D frag

__device__ __forceinline__ unsigned short f2b(float f) {
    __hip_bfloat16 h = __float2bfloat16(f);
    return *reinterpret_cast<unsigned short*>(&h);
}

// ---------------------------------------------------------------------------
// Kernel 1: q/k/v = x @ {Wq,Wk,Wv} -> bf16.  q has softmax scale folded in.
// v is written TRANSPOSED per batch: vt[(b*256 + col)*2048 + key], so the
// attention kernel's PV B-fragments are contiguous 16B loads.
// ---------------------------------------------------------------------------
__global__ void qkv_proj(const float* __restrict__ x,
                         const float* __restrict__ Wq,
                         const float* __restrict__ Wk,
                         const float* __restrict__ Wv,
                         unsigned short* __restrict__ qo,
                         unsigned short* __restrict__ ko,
                         unsigned short* __restrict__ vt) {
    __shared__ float xs[16][DIM];
    const int t  = threadIdx.x;
    const int r0 = blockIdx.x * 16;
    const float* W = (blockIdx.y == 0) ? Wq : (blockIdx.y == 1) ? Wk : Wv;

    for (int idx = t; idx < 16 * DIM; idx += 256) {
        xs[idx >> 8][idx & 255] = x[(size_t)(r0 + (idx >> 8)) * DIM + (idx & 255)];
    }
    __syncthreads();

    float acc[16];
#pragma unroll
    for (int r = 0; r < 16; r++) acc[r] = 0.f;

    for (int kk = 0; kk < DIM; kk++) {
        float w = W[(size_t)kk * DIM + t];
#pragma unroll
        for (int r = 0; r < 16; r++) acc[r] += xs[r][kk] * w;  // xs broadcast
    }

    const float scale = 0.17677669529663687f;  // 1/sqrt(32)
    if (blockIdx.y == 0) {
#pragma unroll
        for (int r = 0; r < 16; r++)
            qo[(size_t)(r0 + r) * DIM + t] = f2b(acc[r] * scale);
    } else if (blockIdx.y == 1) {
#pragma unroll
        for (int r = 0; r < 16; r++)
            ko[(size_t)(r0 + r) * DIM + t] = f2b(acc[r]);
    } else {
#pragma unroll
        for (int r = 0; r < 16; r++) {
            int row = r0 + r;
            int bb  = row >> 11;          // row / 2048
            int key = row & 2047;
            vt[((size_t)(bb * 256 + t)) * SEQ + key] = f2b(acc[r]);
        }
    }
}

// ---------------------------------------------------------------------------
// Kernel 2: MFMA flash attention.  WG = 64 q-rows of one (b,h); 4 waves x 16.
// 16x16x32 bf16 MFMA; K=32 covers the whole head dim in one instruction.
// LDS rows padded to 40 bf16 (80 B): keeps 16B alignment for ds_read_b128
// and <=2-way bank aliasing (free) on fragment reads.
// ---------------------------------------------------------------------------
__global__ __launch_bounds__(256, 2) void attn_mfma(
        const unsigned short* __restrict__ qb,
        const unsigned short* __restrict__ kb,
        const unsigned short* __restrict__ vtb,
        float* __restrict__ attout) {
    __shared__ __align__(16) unsigned short Ks[32][40];
    __shared__ __align__(16) unsigned short Vs[256][40];
    __shared__ __align__(16) unsigned short Ps[4][16][40];

    const int t    = threadIdx.x;
    const int w    = t >> 6;
    const int lane = t & 63;
    const int quad = lane >> 4;
    const int c16  = lane & 15;
    const int h    = blockIdx.y;
    const int b    = blockIdx.z;
    const int i0   = blockIdx.x * 64 + w * 16;   // wave's q-row base in seq

    const size_t qk_head = ((size_t)b * SEQ) * DIM + h * DHEAD;

    // Q fragment (constant over key loop): A[m=c16][k=quad*8+j]
    bf16x8 qf = *(const bf16x8*)&qb[qk_head + (size_t)(i0 + c16) * DIM + quad * 8];

    f32x4 acc[16];
#pragma unroll
    for (int nt = 0; nt < 16; nt++) acc[nt] = (f32x4){0.f, 0.f, 0.f, 0.f};
    float mrow[4] = {-1e30f, -1e30f, -1e30f, -1e30f};
    float lrow[4] = {0.f, 0.f, 0.f, 0.f};
    const f32x4 zero = (f32x4){0.f, 0.f, 0.f, 0.f};

    for (int jt = 0; jt < SEQ / 32; jt++) {
        const int j0 = jt * 32;
        __syncthreads();   // prev-iter LDS reads done before overwrite
        // stage K block: 32 keys x 32 dims, 128 x 16B chunks
        if (t < 128) {
            int key = t >> 2, part = t & 3;
            *(bf16x8*)&Ks[key][part * 8] =
                *(const bf16x8*)&kb[qk_head + (size_t)(j0 + key) * DIM + part * 8];
        }
        // stage V^T block: 256 cols x 32 keys, 1024 x 16B chunks
        {
            const size_t vbase = ((size_t)b * 256) * SEQ + j0;
#pragma unroll
            for (int i = 0; i < 4; i++) {
                int id = t + i * 256;
                int cc = id >> 2, part = id & 3;
                *(bf16x8*)&Vs[cc][part * 8] =
                    *(const bf16x8*)&vtb[vbase + (size_t)cc * SEQ + part * 8];
            }
        }
        __syncthreads();

        // QK^T: S tile 16x32 as two 16x16 MFMAs (scale already folded into q)
        bf16x8 kf0 = *(const bf16x8*)&Ks[c16][quad * 8];
        bf16x8 kf1 = *(const bf16x8*)&Ks[16 + c16][quad * 8];
        f32x4 s0 = __builtin_amdgcn_mfma_f32_16x16x32_bf16(qf, kf0, zero, 0, 0, 0);
        f32x4 s1 = __builtin_amdgcn_mfma_f32_16x16x32_bf16(qf, kf1, zero, 0, 0, 0);

        // online softmax; lane's rows are quad*4+reg, col=c16 (+16 for s1)
        float alpha[4];
#pragma unroll
        for (int reg = 0; reg < 4; reg++) {
            float mx = fmaxf(s0[reg], s1[reg]);
#pragma unroll
            for (int m = 1; m <= 8; m <<= 1) mx = fmaxf(mx, __shfl_xor(mx, m, 64));
            float mn = fmaxf(mrow[reg], mx);
            alpha[reg] = __expf(mrow[reg] - mn);
            mrow[reg] = mn;
            float p0 = __expf(s0[reg] - mn);
            float p1 = __expf(s1[reg] - mn);
            float ps = p0 + p1;
#pragma unroll
            for (int m = 1; m <= 8; m <<= 1) ps += __shfl_xor(ps, m, 64);
            lrow[reg] = lrow[reg] * alpha[reg] + ps;
            // transpose P into LDS (C/D layout -> A layout round trip)
            Ps[w][quad * 4 + reg][c16]      = f2b(p0);
            Ps[w][quad * 4 + reg][16 + c16] = f2b(p1);
        }
        // rescale O accumulators (row = reg)
#pragma unroll
        for (int nt = 0; nt < 16; nt++) {
            acc[nt][0] *= alpha[0];
            acc[nt][1] *= alpha[1];
            acc[nt][2] *= alpha[2];
            acc[nt][3] *= alpha[3];
        }
        __builtin_amdgcn_s_waitcnt(0);  // own-wave P writes visible before read

        // PV: A = P (16x32), B = V block; b_frag rows are V^T rows in LDS
        bf16x8 pf = *(const bf16x8*)&Ps[w][c16][quad * 8];
#pragma unroll
        for (int nt = 0; nt < 16; nt++) {
            bf16x8 vf = *(const bf16x8*)&Vs[nt * 16 + c16][quad * 8];
            acc[nt] = __builtin_amdgcn_mfma_f32_16x16x32_bf16(pf, vf, acc[nt], 0, 0, 0);
        }
    }

    // epilogue: O / l -> attout[b, row, h*256 + col]  (fp32)
#pragma unroll
    for (int reg = 0; reg < 4; reg++) {
        float inv = 1.f / lrow[reg];
        int row = i0 + quad * 4 + reg;
#pragma unroll
        for (int nt = 0; nt < 16; nt++) {
            attout[((size_t)b * SEQ + row) * (HEADS * DIM) + h * DIM + nt * 16 + c16] =
                acc[nt][reg] * inv;
        }
    }
}

// ---------------------------------------------------------------------------
// Kernel 3: out2 = attout @ Wo + x ; ln1 = LayerNorm(out2) * gamma1
// ---------------------------------------------------------------------------
__global__ void wo_ln(const float* __restrict__ attout,
                      const float* __restrict__ Wo,
                      const float* __restrict__ x,
                      const float* __restrict__ gamma1,
                      float* __restrict__ ln1) {
    __shared__ float as_[16][128];
    __shared__ float ob[16][257];   // 257 stride: conflict-free row scans
    __shared__ float mu[16], rs[16];
    const int t  = threadIdx.x;
    const int r0 = blockIdx.x * 16;

    float acc[16];
#pragma unroll
    for (int r = 0; r < 16; r++) acc[r] = 0.f;

    for (int kt = 0; kt < HEADS * DIM; kt += 128) {
        __syncthreads();
        for (int idx = t; idx < 16 * 128; idx += 256) {
            int r = idx >> 7, c = idx & 127;
            as_[r][c] = attout[(size_t)(r0 + r) * (HEADS * DIM) + kt + c];
        }
        __syncthreads();
        for (int kk = 0; kk < 128; kk++) {
            float w = Wo[(size_t)(kt + kk) * DIM + t];
#pragma unroll
            for (int r = 0; r < 16; r++) acc[r] += as_[r][kk] * w;
        }
    }
#pragma unroll
    for (int r = 0; r < 16; r++) {
        acc[r] += x[(size_t)(r0 + r) * DIM + t];
        ob[r][t] = acc[r];
    }
    __syncthreads();
    if (t < 16) {
        float s = 0.f, s2 = 0.f;
        for (int c = 0; c < DIM; c++) { float vv = ob[t][c]; s += vv; s2 += vv * vv; }
        float m = s * (1.0f / DIM);
        float var = s2 * (1.0f / DIM) - m * m;
        mu[t] = m;
        rs[t] = rsqrtf(var + EPS);
    }
    __syncthreads();
    const float g = gamma1[t];
#pragma unroll
    for (int r = 0; r < 16; r++) {
        ln1[(size_t)(r0 + r) * DIM + t] = (ob[r][t] - mu[r]) * rs[r] * g;
    }
}

// ---------------------------------------------------------------------------
// Kernel 4: y = relu(ln1 @ Wf1) @ Wf2 ; out = LayerNorm(y) * gamma2  (fp32 out)
// ---------------------------------------------------------------------------
__global__ void ffn_ln(const float* __restrict__ ln1,
                       const float* __restrict__ Wf1,
                       const float* __restrict__ Wf2,
                       const float* __restrict__ gamma2,
                       float* __restrict__ out) {
    __shared__ float xs[16][257];
    __shared__ float hs[16][512];
    __shared__ float mu[16], rs[16];
    const int t  = threadIdx.x;
    const int r0 = blockIdx.x * 16;

    for (int idx = t; idx < 16 * DIM; idx += 256) {
        int r = idx >> 8, c = idx & 255;
        xs[r][c] = ln1[(size_t)(r0 + r) * DIM + c];
    }
    __syncthreads();

    float h0[16], h1[16];
#pragma unroll
    for (int r = 0; r < 16; r++) { h0[r] = 0.f; h1[r] = 0.f; }
    for (int kk = 0; kk < DIM; kk++) {
        float w0 = Wf1[(size_t)kk * 512 + t];
        float w1 = Wf1[(size_t)kk * 512 + t + 256];
#pragma unroll
        for (int r = 0; r < 16; r++) {
            float xv = xs[r][kk];
            h0[r] += xv * w0;
            h1[r] += xv * w1;
        }
    }
#pragma unroll
    for (int r = 0; r < 16; r++) {
        hs[r][t]       = fmaxf(h0[r], 0.f);
        hs[r][t + 256] = fmaxf(h1[r], 0.f);
    }
    __syncthreads();

    float acc[16];
#pragma unroll
    for (int r = 0; r < 16; r++) acc[r] = 0.f;
    for (int kk = 0; kk < 512; kk++) {
        float w = Wf2[(size_t)kk * DIM + t];
#pragma unroll
        for (int r = 0; r < 16; r++) acc[r] += hs[r][kk] * w;  // hs broadcast
    }

    // LayerNorm 2 (reuse xs as the row buffer)
#pragma unroll
    for (int r = 0; r < 16; r++) xs[r][t] = acc[r];
    __syncthreads();
    if (t < 16) {
        float s = 0.f, s2 = 0.f;
        for (int c = 0; c < DIM; c++) { float vv = xs[t][c]; s += vv; s2 += vv * vv; }
        float m = s * (1.0f / DIM);
        float var = s2 * (1.0f / DIM) - m * m;
        mu[t] = m;
        rs[t] = rsqrtf(var + EPS);
    }
    __syncthreads();
    const float g = gamma2[t];
#pragma unroll
    for (int r = 0; r < 16; r++) {
        out[(size_t)(r0 + r) * DIM + t] = (xs[r][t] - mu[r]) * rs[r] * g;
    }
}

// ---------------------------------------------------------------------------
extern "C" void kernel_launch(void* const* d_in, const int* in_sizes, int n_in,
                              void* d_out, int out_size, void* d_ws, size_t ws_size,
                              hipStream_t stream) {
    const float* x      = (const float*)d_in[0];
    const float* Wq     = (const float*)d_in[1];
    const float* Wk     = (const float*)d_in[2];
    const float* Wv     = (const float*)d_in[3];
    const float* Wo     = (const float*)d_in[4];
    const float* Wf1    = (const float*)d_in[5];
    const float* Wf2    = (const float*)d_in[6];
    const float* gamma1 = (const float*)d_in[7];
    const float* gamma2 = (const float*)d_in[8];
    float* out = (float*)d_out;

    // workspace layout:
    unsigned short* wsu = (unsigned short*)d_ws;
    unsigned short* qb  = wsu;                    // 4096*256 bf16  (2 MB)
    unsigned short* kb  = wsu + 1048576;          // 4096*256 bf16  (2 MB)
    unsigned short* vtb = wsu + 2097152;          // 2*256*2048 bf16 (2 MB, transposed)
    float* attout = (float*)(wsu + 3145728);      // 4096*2048 fp32 (32 MB)
    float* ln1    = attout + (size_t)NROWS * (HEADS * DIM);  // 4096*256 fp32 (4 MB)

    qkv_proj<<<dim3(NROWS / 16, 3), 256, 0, stream>>>(x, Wq, Wk, Wv, qb, kb, vtb);
    attn_mfma<<<dim3(SEQ / 64, HEADS, BATCH), 256, 0, stream>>>(qb, kb, vtb, attout);
    wo_ln<<<NROWS / 16, 256, 0, stream>>>(attout, Wo, x, gamma1, ln1);
    ffn_ln<<<NROWS / 16, 256, 0, stream>>>(ln1, Wf1, Wf2, gamma2, out);
}

// Round 7
// 413.666 us; speedup vs baseline: 5.0584x; 1.2212x over previous
//
#include <hip/hip_runtime.h>
#include <hip/hip_bf16.h>

#define DIM 256
#define HEADS 8
#define DHEAD 32
#define SEQ 2048
#define BATCH 2
#define NROWS (BATCH*SEQ)    // 4096 total rows
#define EPS 1e-5f

typedef __attribute__((ext_vector_type(8))) short bf16x8;   // MFMA A/B frag (4 VGPRs)
typedef __attribute__((ext_vector_type(4))) float f32x4;    // MFMA C/D frag

__device__ __forceinline__ unsigned short f2b(float f) {
    __hip_bfloat16 h = __float2bfloat16(f);
    return *reinterpret_cast<unsigned short*>(&h);
}

__device__ __forceinline__ bf16x8 cvt8(float4 a, float4 b) {
    bf16x8 r;
    r[0] = (short)f2b(a.x); r[1] = (short)f2b(a.y);
    r[2] = (short)f2b(a.z); r[3] = (short)f2b(a.w);
    r[4] = (short)f2b(b.x); r[5] = (short)f2b(b.y);
    r[6] = (short)f2b(b.z); r[7] = (short)f2b(b.w);
    return r;
}

// ---------------------------------------------------------------------------
// Kernel 1 (VERBATIM round 4, passed): q/k/v = x @ {Wq,Wk,Wv} -> bf16.
// ---------------------------------------------------------------------------
__global__ void qkv_proj(const float* __restrict__ x,
                         const float* __restrict__ Wq,
                         const float* __restrict__ Wk,
                         const float* __restrict__ Wv,
                         unsigned short* __restrict__ qo,
                         unsigned short* __restrict__ ko,
                         unsigned short* __restrict__ vt) {
    __shared__ float xs[16][DIM];
    const int t  = threadIdx.x;
    const int r0 = blockIdx.x * 16;
    const float* W = (blockIdx.y == 0) ? Wq : (blockIdx.y == 1) ? Wk : Wv;

    for (int idx = t; idx < 16 * DIM; idx += 256) {
        xs[idx >> 8][idx & 255] = x[(size_t)(r0 + (idx >> 8)) * DIM + (idx & 255)];
    }
    __syncthreads();

    float acc[16];
#pragma unroll
    for (int r = 0; r < 16; r++) acc[r] = 0.f;

    for (int kk = 0; kk < DIM; kk++) {
        float w = W[(size_t)kk * DIM + t];
#pragma unroll
        for (int r = 0; r < 16; r++) acc[r] += xs[r][kk] * w;  // xs broadcast
    }

    const float scale = 0.17677669529663687f;  // 1/sqrt(32)
    if (blockIdx.y == 0) {
#pragma unroll
        for (int r = 0; r < 16; r++)
            qo[(size_t)(r0 + r) * DIM + t] = f2b(acc[r] * scale);
    } else if (blockIdx.y == 1) {
#pragma unroll
        for (int r = 0; r < 16; r++)
            ko[(size_t)(r0 + r) * DIM + t] = f2b(acc[r]);
    } else {
#pragma unroll
        for (int r = 0; r < 16; r++) {
            int row = r0 + r;
            int bb  = row >> 11;          // row / 2048
            int key = row & 2047;
            vt[((size_t)(bb * 256 + t)) * SEQ + key] = f2b(acc[r]);
        }
    }
}

// ---------------------------------------------------------------------------
// Kernel 2 (VERBATIM round 4, passed): MFMA flash attention, fp32 attout.
// ---------------------------------------------------------------------------
__global__ __launch_bounds__(256, 2) void attn_mfma(
        const unsigned short* __restrict__ qb,
        const unsigned short* __restrict__ kb,
        const unsigned short* __restrict__ vtb,
        float* __restrict__ attout) {
    __shared__ __align__(16) unsigned short Ks[32][40];
    __shared__ __align__(16) unsigned short Vs[256][40];
    __shared__ __align__(16) unsigned short Ps[4][16][40];

    const int t    = threadIdx.x;
    const int w    = t >> 6;
    const int lane = t & 63;
    const int quad = lane >> 4;
    const int c16  = lane & 15;
    const int h    = blockIdx.y;
    const int b    = blockIdx.z;
    const int i0   = blockIdx.x * 64 + w * 16;

    const size_t qk_head = ((size_t)b * SEQ) * DIM + h * DHEAD;

    bf16x8 qf = *(const bf16x8*)&qb[qk_head + (size_t)(i0 + c16) * DIM + quad * 8];

    f32x4 acc[16];
#pragma unroll
    for (int nt = 0; nt < 16; nt++) acc[nt] = (f32x4){0.f, 0.f, 0.f, 0.f};
    float mrow[4] = {-1e30f, -1e30f, -1e30f, -1e30f};
    float lrow[4] = {0.f, 0.f, 0.f, 0.f};
    const f32x4 zero = (f32x4){0.f, 0.f, 0.f, 0.f};

    for (int jt = 0; jt < SEQ / 32; jt++) {
        const int j0 = jt * 32;
        __syncthreads();
        if (t < 128) {
            int key = t >> 2, part = t & 3;
            *(bf16x8*)&Ks[key][part * 8] =
                *(const bf16x8*)&kb[qk_head + (size_t)(j0 + key) * DIM + part * 8];
        }
        {
            const size_t vbase = ((size_t)b * 256) * SEQ + j0;
#pragma unroll
            for (int i = 0; i < 4; i++) {
                int id = t + i * 256;
                int cc = id >> 2, part = id & 3;
                *(bf16x8*)&Vs[cc][part * 8] =
                    *(const bf16x8*)&vtb[vbase + (size_t)cc * SEQ + part * 8];
            }
        }
        __syncthreads();

        bf16x8 kf0 = *(const bf16x8*)&Ks[c16][quad * 8];
        bf16x8 kf1 = *(const bf16x8*)&Ks[16 + c16][quad * 8];
        f32x4 s0 = __builtin_amdgcn_mfma_f32_16x16x32_bf16(qf, kf0, zero, 0, 0, 0);
        f32x4 s1 = __builtin_amdgcn_mfma_f32_16x16x32_bf16(qf, kf1, zero, 0, 0, 0);

        float alpha[4];
#pragma unroll
        for (int reg = 0; reg < 4; reg++) {
            float mx = fmaxf(s0[reg], s1[reg]);
#pragma unroll
            for (int m = 1; m <= 8; m <<= 1) mx = fmaxf(mx, __shfl_xor(mx, m, 64));
            float mn = fmaxf(mrow[reg], mx);
            alpha[reg] = __expf(mrow[reg] - mn);
            mrow[reg] = mn;
            float p0 = __expf(s0[reg] - mn);
            float p1 = __expf(s1[reg] - mn);
            float ps = p0 + p1;
#pragma unroll
            for (int m = 1; m <= 8; m <<= 1) ps += __shfl_xor(ps, m, 64);
            lrow[reg] = lrow[reg] * alpha[reg] + ps;
            Ps[w][quad * 4 + reg][c16]      = f2b(p0);
            Ps[w][quad * 4 + reg][16 + c16] = f2b(p1);
        }
#pragma unroll
        for (int nt = 0; nt < 16; nt++) {
            acc[nt][0] *= alpha[0];
            acc[nt][1] *= alpha[1];
            acc[nt][2] *= alpha[2];
            acc[nt][3] *= alpha[3];
        }
        __builtin_amdgcn_s_waitcnt(0);

        bf16x8 pf = *(const bf16x8*)&Ps[w][c16][quad * 8];
#pragma unroll
        for (int nt = 0; nt < 16; nt++) {
            bf16x8 vf = *(const bf16x8*)&Vs[nt * 16 + c16][quad * 8];
            acc[nt] = __builtin_amdgcn_mfma_f32_16x16x32_bf16(pf, vf, acc[nt], 0, 0, 0);
        }
    }

#pragma unroll
    for (int reg = 0; reg < 4; reg++) {
        float inv = 1.f / lrow[reg];
        int row = i0 + quad * 4 + reg;
#pragma unroll
        for (int nt = 0; nt < 16; nt++) {
            attout[((size_t)b * SEQ + row) * (size_t)(HEADS * DIM) + h * DIM + nt * 16 + c16] =
                acc[nt][reg] * inv;
        }
    }
}

// ---------------------------------------------------------------------------
// Kernel 3 (NEW, minimal): WoT[n][k] = bf16(Wo[k][n]).  [256][2048]
// ---------------------------------------------------------------------------
__global__ void wprep(const float* __restrict__ Wo,
                      unsigned short* __restrict__ WoT) {
    const int tid = blockIdx.x * 256 + threadIdx.x;
    const int stride = gridDim.x * 256;
    for (int i = tid; i < 256 * 2048; i += stride) {
        int n = i >> 11, k = i & 2047;
        WoT[i] = f2b(Wo[k * 256 + n]);
    }
}

// ---------------------------------------------------------------------------
// Kernel 4 (NEW — the single change under test): MFMA wo + residual + LN1.
// A = fp32 attout rows (in-kernel bf16 cvt), B = WoT.  16 rows x 256 cols.
// ---------------------------------------------------------------------------
__global__ __launch_bounds__(256) void wo_ln_mfma(
        const float* __restrict__ attout,        // [4096][2048] fp32
        const unsigned short* __restrict__ WoT,  // [256][2048] bf16
        const float* __restrict__ x,
        const float* __restrict__ gamma1,
        float* __restrict__ ln1) {
    __shared__ float Ct[16][264];
    __shared__ float ps1[16][16], ps2[16][16];
    __shared__ float mu[16], rsd[16];

    const int t    = threadIdx.x;
    const int w    = t >> 6;
    const int lane = t & 63;
    const int quad = lane >> 4;
    const int c16  = lane & 15;
    const int r0   = blockIdx.x * 16;

    const float* arow = attout + (size_t)(r0 + c16) * 2048 + quad * 8;

    f32x4 acc[4];
#pragma unroll
    for (int nt = 0; nt < 4; nt++) acc[nt] = (f32x4){0.f, 0.f, 0.f, 0.f};

#pragma unroll 2
    for (int kc = 0; kc < 2048; kc += 32) {
        float4 a0 = *(const float4*)(arow + kc);
        float4 a1 = *(const float4*)(arow + kc + 4);
        bf16x8 afg = cvt8(a0, a1);
#pragma unroll
        for (int nt = 0; nt < 4; nt++) {
            const int n0 = w * 64 + nt * 16;
            bf16x8 bfg = *(const bf16x8*)&WoT[(size_t)(n0 + c16) * 2048 + kc + quad * 8];
            acc[nt] = __builtin_amdgcn_mfma_f32_16x16x32_bf16(afg, bfg, acc[nt], 0, 0, 0);
        }
    }

    // residual + stash (C/D layout: row=quad*4+reg, col=n0+c16)
#pragma unroll
    for (int reg = 0; reg < 4; reg++) {
        const int row = quad * 4 + reg;
#pragma unroll
        for (int nt = 0; nt < 4; nt++) {
            const int col = w * 64 + nt * 16 + c16;
            Ct[row][col] = acc[nt][reg] + x[(size_t)(r0 + row) * 256 + col];
        }
    }
    __syncthreads();
    {   // 2-stage row reduction
        const int row = t >> 4, seg = t & 15;
        float s = 0.f, s2 = 0.f;
#pragma unroll
        for (int j = 0; j < 16; j++) { float v = Ct[row][seg * 16 + j]; s += v; s2 += v * v; }
        ps1[row][seg] = s; ps2[row][seg] = s2;
    }
    __syncthreads();
    if (t < 16) {
        float s = 0.f, s2 = 0.f;
#pragma unroll
        for (int j = 0; j < 16; j++) { s += ps1[t][j]; s2 += ps2[t][j]; }
        float m = s * (1.0f / 256.0f);
        float var = s2 * (1.0f / 256.0f) - m * m;
        mu[t] = m; rsd[t] = rsqrtf(var + EPS);
    }
    __syncthreads();
    const float g = gamma1[t];
#pragma unroll
    for (int r = 0; r < 16; r++)
        ln1[(size_t)(r0 + r) * 256 + t] = (Ct[r][t] - mu[r]) * rsd[r] * g;
}

// ---------------------------------------------------------------------------
// Kernel 5 (VERBATIM round 4, passed): fp32 FFN + LN2.
// ---------------------------------------------------------------------------
__global__ void ffn_ln(const float* __restrict__ ln1,
                       const float* __restrict__ Wf1,
                       const float* __restrict__ Wf2,
                       const float* __restrict__ gamma2,
                       float* __restrict__ out) {
    __shared__ float xs[16][257];
    __shared__ float hs[16][512];
    __shared__ float mu[16], rs[16];
    const int t  = threadIdx.x;
    const int r0 = blockIdx.x * 16;

    for (int idx = t; idx < 16 * DIM; idx += 256) {
        int r = idx >> 8, c = idx & 255;
        xs[r][c] = ln1[(size_t)(r0 + r) * DIM + c];
    }
    __syncthreads();

    float h0[16], h1[16];
#pragma unroll
    for (int r = 0; r < 16; r++) { h0[r] = 0.f; h1[r] = 0.f; }
    for (int kk = 0; kk < DIM; kk++) {
        float w0 = Wf1[(size_t)kk * 512 + t];
        float w1 = Wf1[(size_t)kk * 512 + t + 256];
#pragma unroll
        for (int r = 0; r < 16; r++) {
            float xv = xs[r][kk];
            h0[r] += xv * w0;
            h1[r] += xv * w1;
        }
    }
#pragma unroll
    for (int r = 0; r < 16; r++) {
        hs[r][t]       = fmaxf(h0[r], 0.f);
        hs[r][t + 256] = fmaxf(h1[r], 0.f);
    }
    __syncthreads();

    float acc[16];
#pragma unroll
    for (int r = 0; r < 16; r++) acc[r] = 0.f;
    for (int kk = 0; kk < 512; kk++) {
        float w = Wf2[(size_t)kk * DIM + t];
#pragma unroll
        for (int r = 0; r < 16; r++) acc[r] += hs[r][kk] * w;  // hs broadcast
    }

#pragma unroll
    for (int r = 0; r < 16; r++) xs[r][t] = acc[r];
    __syncthreads();
    if (t < 16) {
        float s = 0.f, s2 = 0.f;
        for (int c = 0; c < DIM; c++) { float vv = xs[t][c]; s += vv; s2 += vv * vv; }
        float m = s * (1.0f / DIM);
        float var = s2 * (1.0f / DIM) - m * m;
        mu[t] = m;
        rs[t] = rsqrtf(var + EPS);
    }
    __syncthreads();
    const float g = gamma2[t];
#pragma unroll
    for (int r = 0; r < 16; r++) {
        out[(size_t)(r0 + r) * DIM + t] = (xs[r][t] - mu[r]) * rs[r] * g;
    }
}

// ---------------------------------------------------------------------------
extern "C" void kernel_launch(void* const* d_in, const int* in_sizes, int n_in,
                              void* d_out, int out_size, void* d_ws, size_t ws_size,
                              hipStream_t stream) {
    const float* x      = (const float*)d_in[0];
    const float* Wq     = (const float*)d_in[1];
    const float* Wk     = (const float*)d_in[2];
    const float* Wv     = (const float*)d_in[3];
    const float* Wo     = (const float*)d_in[4];
    const float* Wf1    = (const float*)d_in[5];
    const float* Wf2    = (const float*)d_in[6];
    const float* gamma1 = (const float*)d_in[7];
    const float* gamma2 = (const float*)d_in[8];
    float* out = (float*)d_out;

    // workspace layout: round-4 layout verbatim, WoT appended (within 48 MiB).
    char* base = (char*)d_ws;
    unsigned short* qb  = (unsigned short*)(base);              // 2 MB
    unsigned short* kb  = (unsigned short*)(base +  2097152);   // 2 MB
    unsigned short* vtb = (unsigned short*)(base +  4194304);   // 2 MB
    float* attout       = (float*)         (base +  6291456);   // 32 MB
    float* ln1          = (float*)         (base + 39845888);   // 4 MB
    unsigned short* WoT = (unsigned short*)(base + 44040192);   // 1 MB -> ends 45088768

    wprep<<<64, 256, 0, stream>>>(Wo, WoT);
    qkv_proj<<<dim3(NROWS / 16, 3), 256, 0, stream>>>(x, Wq, Wk, Wv, qb, kb, vtb);
    attn_mfma<<<dim3(SEQ / 64, HEADS, BATCH), 256, 0, stream>>>(qb, kb, vtb, attout);
    wo_ln_mfma<<<NROWS / 16, 256, 0, stream>>>(attout, WoT, x, gamma1, ln1);
    ffn_ln<<<NROWS / 16, 256, 0, stream>>>(ln1, Wf1, Wf2, gamma2, out);
}